// Round 11
// baseline (402.880 us; speedup 1.0000x reference)
//
#include <hip/hip_runtime.h>
#include <math.h>

// Problem constants (from reference)
#define N_ROWS    16384
#define NC        1000
#define KVAL      5.0f
#define ALPHA     0.025f
#define N_ITER    80
#define MAX_SOLVE 12        // Newton passes; warm-started, early-exits in 1-3
#define EPS_P     1e-6f
#define EPJ       16        // elements per lane: 16*64 = 1024 >= 1000
#define ALN2      0.0173286795139986f   // ALPHA * ln(2)
#define N_ACC     256       // distributed loss accumulators

// One 64-thread block (= one wave) per row; lane holds elements e = j*64+lane.
// State is cc[16] + v[16] + scalars only (p == relu(v - nu), recomputed).
// Period-2 detection: fingerprint {nu, m, sum(v*cc), sum(v*w)} compared
// against ONE check back (= 2 iterations back). R10 compared two checks back
// (4 iterations) -- same hits, +2 iters latency per row (~13% of kernel).
// Finalize is fused: after its atomicAdd each block takes a ticket; the
// holder of ticket N_ROWS-1 (all adds fenced & visible) reduces the 256
// accumulators via atomic reads (device coherence point -- per-XCD L2 is not
// coherent for plain loads, G16) and writes the mean. No finalize dispatch.
//
// R7 lesson: live state must fit the launch-bounds register cap -- (64,6)
// gives ~80/lane, actual ~50 -> no spill (WRITE_SIZE stays ~KB: tripwire).
// Solver invariants (R4/R5): v in [0.11,0.92] => upper clip never binds,
// nu* > 0, s(nu)=sum relu(v-nu) convex piecewise-linear => warm-started
// Newton converges globally & monotonically after one step.

template <int CTRL>
__device__ __forceinline__ float dpp_add(float x) {
    int t = __builtin_amdgcn_update_dpp(0, __float_as_int(x), CTRL, 0xf, 0xf, true);
    return x + __int_as_float(t);
}

// Full 64-lane sum -> uniform via readlane(63).
__device__ __forceinline__ float wave_sum(float x) {
    x = dpp_add<0x111>(x);  // row_shr:1
    x = dpp_add<0x112>(x);  // row_shr:2
    x = dpp_add<0x114>(x);  // row_shr:4
    x = dpp_add<0x118>(x);  // row_shr:8
    x = dpp_add<0x142>(x);  // row_bcast:15
    x = dpp_add<0x143>(x);  // row_bcast:31 -> lane63 = total
    return __int_as_float(__builtin_amdgcn_readlane(__float_as_int(x), 63));
}

__global__ __launch_bounds__(64, 6) void pgd_kernel(
        const float*  __restrict__ x,
        const int*    __restrict__ y,
        double*       __restrict__ acc,
        unsigned int* __restrict__ ticket,
        float*        __restrict__ out) {
    const int lane = threadIdx.x;
    const int row  = blockIdx.x;
    const bool valid15 = lane < (NC - 15 * 64);  // lane < 40 for j==15

    const float* __restrict__ xr = x + (size_t)row * NC;
    const int yv = y[row];            // prefetch: independent, schedules early
    const float flane = (float)(lane + 1);   // checksum weight base

    float cc[EPJ];  // ALPHA * normalized logits
    float v[EPJ];   // pre-projection iterate; p == relu(v - nu)

    // ---- load row + sum of squares (L2 normalize) ----
    float ss = 0.f;
#pragma unroll
    for (int j = 0; j < EPJ; ++j) {
        const int e = j * 64 + lane;
        float xv = (e < NC) ? xr[e] : 0.f;
        cc[j] = xv;
        ss += xv * xv;
    }
    ss = wave_sum(ss);
    const float sc = ALPHA / fmaxf(sqrtf(ss), 1e-12f);
#pragma unroll
    for (int j = 0; j < EPJ; ++j) cc[j] *= sc;

    // init so relu(v - nu) == p0 = 0.005 exactly (pads: 0)
#pragma unroll
    for (int j = 0; j < EPJ; ++j) v[j] = KVAL / (float)NC;
    if (!valid15) v[15] = 0.f;
    float nu = 0.f;                  // projection shift for current v
    float nu_m1 = 0.f, nu_m2 = 0.f;  // warm-start history

    // fingerprint one check (= 2 iterations) back
    float fA_nu = -1.f, fA_c1 = 0.f, fA_c2 = 0.f;  int fA_m = -1;

    for (int it = 0; it < N_ITER; ++it) {
        // ---- ascent: p = relu(v-nu); v' = p + alpha*c + aln2*(log2(1-pc)-log2(pc)) ----
#pragma unroll
        for (int j = 0; j < EPJ; ++j) {
            float pj = fmaxf(v[j] - nu, 0.f);
            float pc = fmaxf(pj, EPS_P);
            float d  = __log2f(1.f - pc) - __log2f(pc);
            float vj = fmaf(ALN2, d, pj + cc[j]);
            if (j == 15) vj = valid15 ? vj : 0.f;   // pads stay 0 (nu >= 0)
            v[j] = vj;
        }

        // ---- projection: warm-started Newton on convex s(nu)=K ----
        float nu_new = nu_m2;
        int   m_fin  = 0;
        for (int pass = 0; pass < MAX_SOLVE; ++pass) {
            float s = 0.f;
            int   m = 0;
#pragma unroll
            for (int j = 0; j < EPJ; ++j) {
                float t = v[j] - nu_new;
                s += fmaxf(t, 0.f);
                m += (int)__builtin_popcountll(__ballot(t > 0.f));  // slope
            }
            s = wave_sum(s);
            if (m == 0) { nu_new = 0.f; continue; }  // restart below root (s(0)>K)
            m_fin = m;
            float step = (s - KVAL) / (float)m;
            nu_new += step;
            if (fabsf(step) < 3e-8f) break;          // ~1 ULP: converged
        }
        nu_m2 = nu_m1;
        nu_m1 = nu_new;
        nu    = nu_new;   // p_t == relu(v - nu)

        // ---- period-2 fingerprint at odd it (completed count even, like 80) ----
        if (it & 1) {
            float c1 = 0.f, c2 = 0.f;
#pragma unroll
            for (int j = 0; j < EPJ; ++j) {
                c1 = fmaf(v[j], cc[j], c1);
                c2 = fmaf(v[j], flane + (float)(j * 64), c2);
            }
            c1 = wave_sum(c1);
            c2 = wave_sum(c2);
            const bool hit = (__float_as_int(nu) == __float_as_int(fA_nu)) &&
                             (m_fin == fA_m) &&
                             (__float_as_int(c1) == __float_as_int(fA_c1)) &&
                             (__float_as_int(c2) == __float_as_int(fA_c2));
            fA_nu = nu; fA_m = m_fin; fA_c1 = c1; fA_c2 = c2;
            if (hit) break;   // bitwise period-2: state == 2 iterations back
        }
    }

    // ---- pick p[y] = relu(v[y]-nu), loss = -log(p_y + 1e-8) ----
    const int jy = yv >> 6;
    const int ly = yv & 63;
    float sel = 0.f;
#pragma unroll
    for (int j = 0; j < EPJ; ++j) sel = (j == jy) ? v[j] : sel;
    const float vy = __shfl(sel, ly, 64);
    const float py = fminf(fmaxf(vy - nu, 0.f), 1.f);

    // ---- commit + fused finalize (ticket: last block reduces) ----
    int last = 0;
    if (lane == 0) {
        atomicAdd(&acc[row & (N_ACC - 1)], (double)(-logf(py + 1e-8f)));
        __threadfence();                         // add visible before ticket
        unsigned int t = atomicAdd(ticket, 1u);
        last = (t == N_ROWS - 1) ? 1 : 0;
    }
    last = __shfl(last, 0, 64);
    if (last) {
        double s = 0.0;
#pragma unroll
        for (int k = 0; k < N_ACC / 64; ++k)
            s += atomicAdd(&acc[lane + 64 * k], 0.0);   // coherent read (G16)
#pragma unroll
        for (int m = 32; m >= 1; m >>= 1) s += __shfl_down(s, m, 64);
        if (lane == 0) out[0] = (float)(s / (double)N_ROWS);
    }
}

extern "C" void kernel_launch(void* const* d_in, const int* in_sizes, int n_in,
                              void* d_out, int out_size, void* d_ws, size_t ws_size,
                              hipStream_t stream) {
    const float* x = (const float*)d_in[0];
    const int*   y = (const int*)d_in[1];
    double*       acc    = (double*)d_ws;                          // 256 * 8 B
    unsigned int* ticket = (unsigned int*)((char*)d_ws + N_ACC * sizeof(double));

    (void)hipMemsetAsync(d_ws, 0, N_ACC * sizeof(double) + sizeof(unsigned int),
                         stream);                // ws poisoned 0xAA each call
    pgd_kernel<<<N_ROWS, 64, 0, stream>>>(x, y, acc, ticket, (float*)d_out);
}

// Round 12
// 245.873 us; speedup vs baseline: 1.6386x; 1.6386x over previous
//
#include <hip/hip_runtime.h>
#include <math.h>

// Problem constants (from reference)
#define N_ROWS    16384
#define NC        1000
#define KVAL      5.0f
#define ALPHA     0.025f
#define N_ITER    80
#define MAX_SOLVE 12        // Newton passes; warm-started, early-exits in 1-3
#define EPS_P     1e-6f
#define EPJ       16        // elements per lane: 16*64 = 1024 >= 1000
#define ALN2      0.0173286795139986f   // ALPHA * ln(2)
#define N_ACC     256       // distributed loss accumulators

// One 64-thread block (= one wave) per row; lane holds elements e = j*64+lane.
// State is cc[16] + v[16] + scalars only (p == relu(v - nu), recomputed).
// Period-2 detection: fingerprint {nu, m, sum(v*cc), sum(v*w)} compared one
// check back (= 2 iterations). Verified bit-exact in R11 (absmax 0.0).
//
// R11 lesson: do NOT fuse the finalize via a single ticket counter — 16384
// returning atomics on one address serialize at the L2 bank (~30 cy each
// => ~200 us) and drag VALUBusy 93% -> 23%. Separate 1-wave finalize kernel
// costs only the graph-internal dispatch gap.
// R7 lesson: live state must fit the launch-bounds register cap — (64,6)
// gives ~80/lane, actual ~50 -> no spill (WRITE_SIZE ~512 B: tripwire).
// Solver invariants (R4/R5): v in [0.11,0.92] => upper clip never binds,
// nu* > 0, s(nu)=sum relu(v-nu) convex piecewise-linear => warm-started
// Newton converges globally & monotonically after one step.

template <int CTRL>
__device__ __forceinline__ float dpp_add(float x) {
    int t = __builtin_amdgcn_update_dpp(0, __float_as_int(x), CTRL, 0xf, 0xf, true);
    return x + __int_as_float(t);
}

// Full 64-lane sum -> uniform via readlane(63).
__device__ __forceinline__ float wave_sum(float x) {
    x = dpp_add<0x111>(x);  // row_shr:1
    x = dpp_add<0x112>(x);  // row_shr:2
    x = dpp_add<0x114>(x);  // row_shr:4
    x = dpp_add<0x118>(x);  // row_shr:8
    x = dpp_add<0x142>(x);  // row_bcast:15
    x = dpp_add<0x143>(x);  // row_bcast:31 -> lane63 = total
    return __int_as_float(__builtin_amdgcn_readlane(__float_as_int(x), 63));
}

__global__ __launch_bounds__(64, 6) void pgd_kernel(
        const float* __restrict__ x,
        const int*   __restrict__ y,
        double*      __restrict__ acc) {
    const int lane = threadIdx.x;
    const int row  = blockIdx.x;
    const bool valid15 = lane < (NC - 15 * 64);  // lane < 40 for j==15

    const float* __restrict__ xr = x + (size_t)row * NC;
    const int yv = y[row];            // prefetch: independent, schedules early
    const float flane = (float)(lane + 1);   // checksum weight base

    float cc[EPJ];  // ALPHA * normalized logits
    float v[EPJ];   // pre-projection iterate; p == relu(v - nu)

    // ---- load row + sum of squares (L2 normalize) ----
    float ss = 0.f;
#pragma unroll
    for (int j = 0; j < EPJ; ++j) {
        const int e = j * 64 + lane;
        float xv = (e < NC) ? xr[e] : 0.f;
        cc[j] = xv;
        ss += xv * xv;
    }
    ss = wave_sum(ss);
    const float sc = ALPHA / fmaxf(sqrtf(ss), 1e-12f);
#pragma unroll
    for (int j = 0; j < EPJ; ++j) cc[j] *= sc;

    // init so relu(v - nu) == p0 = 0.005 exactly (pads: 0)
#pragma unroll
    for (int j = 0; j < EPJ; ++j) v[j] = KVAL / (float)NC;
    if (!valid15) v[15] = 0.f;
    float nu = 0.f;                  // projection shift for current v
    float nu_m1 = 0.f, nu_m2 = 0.f;  // warm-start history

    // fingerprint one check (= 2 iterations) back
    float fA_nu = -1.f, fA_c1 = 0.f, fA_c2 = 0.f;  int fA_m = -1;

    for (int it = 0; it < N_ITER; ++it) {
        // ---- ascent: p = relu(v-nu); v' = p + alpha*c + aln2*(log2(1-pc)-log2(pc)) ----
#pragma unroll
        for (int j = 0; j < EPJ; ++j) {
            float pj = fmaxf(v[j] - nu, 0.f);
            float pc = fmaxf(pj, EPS_P);
            float d  = __log2f(1.f - pc) - __log2f(pc);
            float vj = fmaf(ALN2, d, pj + cc[j]);
            if (j == 15) vj = valid15 ? vj : 0.f;   // pads stay 0 (nu >= 0)
            v[j] = vj;
        }

        // ---- projection: warm-started Newton on convex s(nu)=K ----
        float nu_new = nu_m2;
        int   m_fin  = 0;
        for (int pass = 0; pass < MAX_SOLVE; ++pass) {
            float s = 0.f;
            int   m = 0;
#pragma unroll
            for (int j = 0; j < EPJ; ++j) {
                float t = v[j] - nu_new;
                s += fmaxf(t, 0.f);
                m += (int)__builtin_popcountll(__ballot(t > 0.f));  // slope
            }
            s = wave_sum(s);
            if (m == 0) { nu_new = 0.f; continue; }  // restart below root (s(0)>K)
            m_fin = m;
            float step = (s - KVAL) / (float)m;
            nu_new += step;
            if (fabsf(step) < 3e-8f) break;          // ~1 ULP: converged
        }
        nu_m2 = nu_m1;
        nu_m1 = nu_new;
        nu    = nu_new;   // p_t == relu(v - nu)

        // ---- period-2 fingerprint at odd it (completed count even, like 80) ----
        if (it & 1) {
            float c1 = 0.f, c2 = 0.f;
#pragma unroll
            for (int j = 0; j < EPJ; ++j) {
                c1 = fmaf(v[j], cc[j], c1);
                c2 = fmaf(v[j], flane + (float)(j * 64), c2);
            }
            c1 = wave_sum(c1);
            c2 = wave_sum(c2);
            const bool hit = (__float_as_int(nu) == __float_as_int(fA_nu)) &&
                             (m_fin == fA_m) &&
                             (__float_as_int(c1) == __float_as_int(fA_c1)) &&
                             (__float_as_int(c2) == __float_as_int(fA_c2));
            fA_nu = nu; fA_m = m_fin; fA_c1 = c1; fA_c2 = c2;
            if (hit) break;   // bitwise period-2: state == 2 iterations back
        }
    }

    // ---- pick p[y] = relu(v[y]-nu), loss = -log(p_y + 1e-8) ----
    const int jy = yv >> 6;
    const int ly = yv & 63;
    float sel = 0.f;
#pragma unroll
    for (int j = 0; j < EPJ; ++j) sel = (j == jy) ? v[j] : sel;
    const float vy = __shfl(sel, ly, 64);
    const float py = fminf(fmaxf(vy - nu, 0.f), 1.f);

    if (lane == 0)
        atomicAdd(&acc[row & (N_ACC - 1)], (double)(-logf(py + 1e-8f)));
}

__global__ void finalize_kernel(const double* __restrict__ acc,
                                float* __restrict__ out) {
    const int l = threadIdx.x;      // 64 lanes
    double s = acc[l] + acc[l + 64] + acc[l + 128] + acc[l + 192];
#pragma unroll
    for (int m = 32; m >= 1; m >>= 1) s += __shfl_down(s, m, 64);
    if (l == 0) out[0] = (float)(s / (double)N_ROWS);
}

extern "C" void kernel_launch(void* const* d_in, const int* in_sizes, int n_in,
                              void* d_out, int out_size, void* d_ws, size_t ws_size,
                              hipStream_t stream) {
    const float* x = (const float*)d_in[0];
    const int*   y = (const int*)d_in[1];
    double* acc = (double*)d_ws;

    (void)hipMemsetAsync(acc, 0, N_ACC * sizeof(double), stream);  // ws poisoned 0xAA
    pgd_kernel<<<N_ROWS, 64, 0, stream>>>(x, y, acc);
    finalize_kernel<<<1, 64, 0, stream>>>(acc, (float*)d_out);
}

// Round 14
// 162.910 us; speedup vs baseline: 2.4730x; 1.5093x over previous
//
#include <hip/hip_runtime.h>
#include <math.h>

// Problem constants (from reference)
#define N_ROWS    16384
#define NC        1000
#define KVAL      5.0f
#define ALPHA     0.025f
#define N_ITER    80
#define MAX_SOLVE 12        // Newton passes; warm-started, early-exits in 1-3
#define EPS_P     1e-6f
#define EPJ       16        // elements per lane: 16*64 = 1024 >= 1000
#define ALN2      0.0173286795139986f   // ALPHA * ln(2)
#define N_ACC     256       // distributed loss accumulators

// RESUBMIT of R13 unchanged: R13 died in a pytest core dump with no HIP error
// and no counter data — kernel diff vs passing R12/R10 is 4 scalar registers
// + 4 integer compares (no new memory ops), no fault mechanism. Treating as
// infra flake; identical source for a clean A/B.
//
// One 64-thread block (= one wave) per row; lane holds elements e = j*64+lane.
// State: cc[16] + v[16] + scalars (p == relu(v - nu), recomputed).
//
// CYCLE DETECTION (R10/R12 lesson): most rows lock into a bitwise period-2
// flush cycle, but a ~3% subpopulation is bitwise period-4 — the warm-start
// recursion nu(t) = f(v(t), nu(t-2)) settles into a 2-cycle on the nu
// odd/even chains (Newton step dithers around the 3e-8 tolerance), so the
// full state only repeats at distance 4. A 2-back-only detector (R6/R9/R12)
// misses them -> those rows run all 80 iters -> long low-occupancy tail
// (VALU 42-48%, wall ~2x). A 4-back-only detector (R10) catches everything
// but adds +2 iters lag on the period-2 majority. Fire on EITHER: both break
// rules are individually verified reference-exact (absmax 0.0 in R12 / R10).
//
// R11 lesson: no single-address returning-atomic ticket (serializes ~200 us).
// R7 lesson: state must fit the launch-bounds cap — (64,6) ~80 regs/lane,
// actual ~50 -> no spill (WRITE_SIZE ~512 B is the tripwire).
// Solver invariants (R4/R5): v in [0.11,0.92] => upper clip never binds,
// nu* > 0, s(nu)=sum relu(v-nu) convex piecewise-linear => warm-started
// Newton converges globally & monotonically after one step.

template <int CTRL>
__device__ __forceinline__ float dpp_add(float x) {
    int t = __builtin_amdgcn_update_dpp(0, __float_as_int(x), CTRL, 0xf, 0xf, true);
    return x + __int_as_float(t);
}

// Full 64-lane sum -> uniform via readlane(63).
__device__ __forceinline__ float wave_sum(float x) {
    x = dpp_add<0x111>(x);  // row_shr:1
    x = dpp_add<0x112>(x);  // row_shr:2
    x = dpp_add<0x114>(x);  // row_shr:4
    x = dpp_add<0x118>(x);  // row_shr:8
    x = dpp_add<0x142>(x);  // row_bcast:15
    x = dpp_add<0x143>(x);  // row_bcast:31 -> lane63 = total
    return __int_as_float(__builtin_amdgcn_readlane(__float_as_int(x), 63));
}

__global__ __launch_bounds__(64, 6) void pgd_kernel(
        const float* __restrict__ x,
        const int*   __restrict__ y,
        double*      __restrict__ acc) {
    const int lane = threadIdx.x;
    const int row  = blockIdx.x;
    const bool valid15 = lane < (NC - 15 * 64);  // lane < 40 for j==15

    const float* __restrict__ xr = x + (size_t)row * NC;
    const int yv = y[row];            // prefetch: independent, schedules early
    const float flane = (float)(lane + 1);   // checksum weight base

    float cc[EPJ];  // ALPHA * normalized logits
    float v[EPJ];   // pre-projection iterate; p == relu(v - nu)

    // ---- load row + sum of squares (L2 normalize) ----
    float ss = 0.f;
#pragma unroll
    for (int j = 0; j < EPJ; ++j) {
        const int e = j * 64 + lane;
        float xv = (e < NC) ? xr[e] : 0.f;
        cc[j] = xv;
        ss += xv * xv;
    }
    ss = wave_sum(ss);
    const float sc = ALPHA / fmaxf(sqrtf(ss), 1e-12f);
#pragma unroll
    for (int j = 0; j < EPJ; ++j) cc[j] *= sc;

    // init so relu(v - nu) == p0 = 0.005 exactly (pads: 0)
#pragma unroll
    for (int j = 0; j < EPJ; ++j) v[j] = KVAL / (float)NC;
    if (!valid15) v[15] = 0.f;
    float nu = 0.f;                  // projection shift for current v
    float nu_m1 = 0.f, nu_m2 = 0.f;  // warm-start history

    // fingerprints: fA = 1 check (2 iters) back, fB = 2 checks (4 iters) back
    float fA_nu = -1.f, fA_c1 = 0.f, fA_c2 = 0.f;  int fA_m = -1;
    float fB_nu = -2.f, fB_c1 = 0.f, fB_c2 = 0.f;  int fB_m = -2;

    for (int it = 0; it < N_ITER; ++it) {
        // ---- ascent: p = relu(v-nu); v' = p + alpha*c + aln2*(log2(1-pc)-log2(pc)) ----
#pragma unroll
        for (int j = 0; j < EPJ; ++j) {
            float pj = fmaxf(v[j] - nu, 0.f);
            float pc = fmaxf(pj, EPS_P);
            float d  = __log2f(1.f - pc) - __log2f(pc);
            float vj = fmaf(ALN2, d, pj + cc[j]);
            if (j == 15) vj = valid15 ? vj : 0.f;   // pads stay 0 (nu >= 0)
            v[j] = vj;
        }

        // ---- projection: warm-started Newton on convex s(nu)=K ----
        float nu_new = nu_m2;
        int   m_fin  = 0;
        for (int pass = 0; pass < MAX_SOLVE; ++pass) {
            float s = 0.f;
            int   m = 0;
#pragma unroll
            for (int j = 0; j < EPJ; ++j) {
                float t = v[j] - nu_new;
                s += fmaxf(t, 0.f);
                m += (int)__builtin_popcountll(__ballot(t > 0.f));  // slope
            }
            s = wave_sum(s);
            if (m == 0) { nu_new = 0.f; continue; }  // restart below root (s(0)>K)
            m_fin = m;
            float step = (s - KVAL) / (float)m;
            nu_new += step;
            if (fabsf(step) < 3e-8f) break;          // ~1 ULP: converged
        }
        nu_m2 = nu_m1;
        nu_m1 = nu_new;
        nu    = nu_new;   // p_t == relu(v - nu)

        // ---- period-2/4 fingerprint at odd it (completed count even, like 80) ----
        if (it & 1) {
            float c1 = 0.f, c2 = 0.f;
#pragma unroll
            for (int j = 0; j < EPJ; ++j) {
                c1 = fmaf(v[j], cc[j], c1);
                c2 = fmaf(v[j], flane + (float)(j * 64), c2);
            }
            c1 = wave_sum(c1);
            c2 = wave_sum(c2);
            const bool hit2 = (__float_as_int(nu) == __float_as_int(fA_nu)) &&
                              (m_fin == fA_m) &&
                              (__float_as_int(c1) == __float_as_int(fA_c1)) &&
                              (__float_as_int(c2) == __float_as_int(fA_c2));
            const bool hit4 = (__float_as_int(nu) == __float_as_int(fB_nu)) &&
                              (m_fin == fB_m) &&
                              (__float_as_int(c1) == __float_as_int(fB_c1)) &&
                              (__float_as_int(c2) == __float_as_int(fB_c2));
            fB_nu = fA_nu; fB_m = fA_m; fB_c1 = fA_c1; fB_c2 = fA_c2;
            fA_nu = nu;    fA_m = m_fin; fA_c1 = c1;   fA_c2 = c2;
            if (hit2 || hit4) break;   // state == 2 or 4 iterations back
        }
    }

    // ---- pick p[y] = relu(v[y]-nu), loss = -log(p_y + 1e-8) ----
    const int jy = yv >> 6;
    const int ly = yv & 63;
    float sel = 0.f;
#pragma unroll
    for (int j = 0; j < EPJ; ++j) sel = (j == jy) ? v[j] : sel;
    const float vy = __shfl(sel, ly, 64);
    const float py = fminf(fmaxf(vy - nu, 0.f), 1.f);

    if (lane == 0)
        atomicAdd(&acc[row & (N_ACC - 1)], (double)(-logf(py + 1e-8f)));
}

__global__ void finalize_kernel(const double* __restrict__ acc,
                                float* __restrict__ out) {
    const int l = threadIdx.x;      // 64 lanes
    double s = acc[l] + acc[l + 64] + acc[l + 128] + acc[l + 192];
#pragma unroll
    for (int m = 32; m >= 1; m >>= 1) s += __shfl_down(s, m, 64);
    if (l == 0) out[0] = (float)(s / (double)N_ROWS);
}

extern "C" void kernel_launch(void* const* d_in, const int* in_sizes, int n_in,
                              void* d_out, int out_size, void* d_ws, size_t ws_size,
                              hipStream_t stream) {
    const float* x = (const float*)d_in[0];
    const int*   y = (const int*)d_in[1];
    double* acc = (double*)d_ws;

    (void)hipMemsetAsync(acc, 0, N_ACC * sizeof(double), stream);  // ws poisoned 0xAA
    pgd_kernel<<<N_ROWS, 64, 0, stream>>>(x, y, acc);
    finalize_kernel<<<1, 64, 0, stream>>>(acc, (float*)d_out);
}